// Round 4
// baseline (138.182 us; speedup 1.0000x reference)
//
#include <hip/hip_runtime.h>
#include <math.h>

// EKF over 2048 trajectories, T=512 serial steps. R12: TWO trajectories per
// lane packed as float2 -> the 22-op fma body issues as v_pk_*_f32 (packed
// dual-FP32, gfx90a+/gfx950), halving issued wave-ops per chain-step. Lane
// 3k+j = subsystem j of trajectories (traj0+k) and (traj0+21+k); 42 traj per
// 64-thread block, grid 49. Transcendentals (2x exp2, 4x rcp per step-pair)
// stay scalar. Per-component math is bit-identical to R11.
//
// Regime (R9-R11 A/B arithmetic): solo wave per SIMD, ~51% issue-active at
// ~1.3 GHz effective; per-step ~127 cyc of which ~65-70 is issue. pk packing
// attacks the issue term; the 2-chain interleave hides most dep-chain stall.
//
// LDS: back to R10's conflict-free layout - two float2 planes (S and m),
// row stride 17 float2 = 34 dwords === 2 (mod 32) -> 2-way max (free, m136).
// ds_write_b64 in-loop with immediate offsets (no addr arithmetic in loop).
// TILE=16 keeps the z double-buffer at 64 VGPRs.

typedef float v2f __attribute__((ext_vector_type(2)));

#define TRIPLES 21               // traj per chain-slot per wave (x2 slots = 42)
#define TILE    16
#define SMS     17               // float2 row stride (16 cols + 1 pad)

__device__ __forceinline__ float frcp(float x) { return __builtin_amdgcn_rcpf(x); }
__device__ __forceinline__ v2f vsplat(float x) { v2f r; r.x = x; r.y = x; return r; }
__device__ __forceinline__ v2f vfma(v2f a, v2f b, v2f c) {
    return __builtin_elementwise_fma(a, b, c);
}

__global__ __launch_bounds__(64, 1) void ekf_kernel(
    const float* __restrict__ meas,        // (n_traj, T, 3)
    const float* __restrict__ init_state,  // (n_traj, 6)
    const float* __restrict__ dyna,        // (4,)
    const float* __restrict__ Qm,          // (6,6)
    const float* __restrict__ Rm,          // (3,3)
    const float* __restrict__ P0m,         // (6,6)
    float* __restrict__ out,               // (n_traj*T,)
    int n_traj, int T)
{
    __shared__ v2f sS[64 * SMS];           // (S_a, S_b) per lane-row
    __shared__ v2f sM[64 * SMS];           // (m_a, m_b) per lane-row

    const int lane  = threadIdx.x;         // 0..63
    const int k     = lane / 3;
    const int j     = lane - 3 * k;        // subsystem 0=x,1=y,2=theta
    const int traj0 = blockIdx.x * (2 * TRIPLES);
    const int kk    = (k < TRIPLES) ? k : (TRIPLES - 1);
    const int tAi   = traj0 + kk;
    const int tBi   = traj0 + TRIPLES + kk;
    const int tA    = (tAi < n_traj) ? tAi : (n_traj - 1);
    const int tB    = (tBi < n_traj) ? tBi : (n_traj - 1);

    const int NT = T / TILE;               // 32
    const int T3 = 3 * T;

    // ---- filter constants (per-lane scalars; same for both chain slots) ----
    const float DTc = 1.0f / 120.0f;
    const float Cc  = 288.53900817779268f; // 200/ln2
    const float invCc2 = 1.0f / (Cc * Cc);
    const float fric = dyna[0], damp = dyna[1];
    const bool  lin = (j == 2);
    const float ca  = lin ? 1.0f : (1.0f - DTc * damp);
    const float cf  = lin ? 0.0f : (DTc * fric);
    const float cb  = 100.0f * cf;
    const float m4cb  = -4.0f * cb;
    const float cf2Cc = 2.0f * (cf * Cc);
    const float mcfCc = -(cf * Cc);
    const int pi = (j == 0) ? 0 : (j == 1) ? 1 : 4;
    const int vi = lin ? 5 : (pi + 2);
    const float qp = Qm[pi * 7], qv = Qm[vi * 7], qc = Qm[pi * 6 + vi];
    const float r   = Rm[j * 4];
    const float nr2 = -r * r;
    const float w0  = r + r + qp;

    // ---- packed state: component x = chain A, y = chain B ----
    v2f p02, p22, w, posC, xv;
    p02 = vsplat(P0m[pi * 6 + vi]);
    p22 = vsplat(P0m[vi * 7]);
    w   = vsplat(P0m[pi * 7] + qp + r);
    posC.x = Cc * init_state[tA * 6 + pi];
    posC.y = Cc * init_state[tB * 6 + pi];
    xv.x   = Cc * init_state[tA * 6 + vi];
    xv.y   = Cc * init_state[tB * 6 + vi];

    // ---- hoisted packed constants ----
    const v2f vDT  = vsplat(DTc),  vCa  = vsplat(ca),   vM4  = vsplat(m4cb);
    const v2f vQc  = vsplat(qc),   vQv  = vsplat(qv),   vR   = vsplat(r);
    const v2f vNr2 = vsplat(nr2),  vW0  = vsplat(w0),   vCc  = vsplat(Cc);
    const v2f vMcf = vsplat(mcfCc), vCf2 = vsplat(cf2Cc);

    // ---- flush mapping: fh = traj row within round, tw = t column ----
    const int fh = lane >> 4;              // 0..3
    const int tw = lane & 15;              // 0..15

    // ---- per-lane z streams (stride-3 floats), double-buffered ----
    const float* __restrict__ zpa = meas + (size_t)tA * T3 + j;
    const float* __restrict__ zpb = meas + (size_t)tB * T3 + j;

    v2f zA[TILE], zB[TILE];
    #pragma unroll
    for (int tl = 0; tl < TILE; ++tl) {
        zA[tl].x = zpa[3 * tl];
        zA[tl].y = zpb[3 * tl];
    }

#define EKF_PHASE(ZC, ZN, TIDX)                                              \
    do {                                                                     \
        const int tile_ = (TIDX);                                            \
        const int nt_   = (tile_ + 1 < NT) ? (tile_ + 1) : tile_;            \
        const float* __restrict__ za_ = zpa + 48 * nt_;                      \
        const float* __restrict__ zb_ = zpb + 48 * nt_;                      \
        _Pragma("unroll")                                                    \
        for (int tl = 0; tl < TILE; ++tl) {                                  \
            ZN[tl].x = za_[3 * tl];                                          \
            ZN[tl].y = zb_[3 * tl];                                          \
        }                                                                    \
        _Pragma("unroll")                                                    \
        for (int tl = 0; tl < TILE; ++tl) {                                  \
            const v2f z   = ZC[tl];                                          \
            v2f e;  e.x  = exp2f(xv.x);  e.y  = exp2f(xv.y);                 \
            const v2f e1  = e + vsplat(1.0f);                                \
            v2f ie; ie.x = frcp(e1.x);   ie.y = frcp(e1.y);                  \
            const v2f t_  = vfma(-ie, ie, ie);      /* ie - ie^2 */          \
            const v2f a   = vfma(vM4, t_, vCa);                              \
            const v2f u   = vfma(vDT, p22, p02);                             \
            const v2f wp  = vfma(vDT, p02, w);                               \
            const v2f S   = vfma(vDT, u, wp);       /* = pp00 + r */         \
            v2f rs; rs.x = frcp(S.x);    rs.y = frcp(S.y);                   \
            const v2f spC = vfma(vDT, xv, posC);                             \
            const v2f yvC = vfma(vCc, z, -spC);                              \
            const v2f rsy = rs * yvC;                                        \
            const v2f pp02 = vfma(a, u, vQc);                                \
            const v2f ap   = a * p22;                                        \
            const v2f pp22 = vfma(ap, a, vQv);                               \
            const v2f svi  = vfma(vCa, xv, vMcf);                            \
            const v2f svC  = vfma(vCf2, ie, svi);                            \
            xv   = vfma(pp02, rsy, svC);                                     \
            const v2f pp00 = S - vR;                                         \
            posC = vfma(pp00, rsy, spC);                                     \
            w    = vfma(vNr2, rs, vW0);                                      \
            const v2f k1 = pp02 * rs;                                        \
            p02 = vR * k1;                                                   \
            p22 = vfma(-k1, pp02, pp22);                                     \
            sS[lane * SMS + tl] = S;                                         \
            sM[lane * SMS + tl] = yvC * rsy;  /* Cc^2 y^2/S */               \
        }                                                                    \
        /* flush: 6 rounds, packed loss for chain A (.x) and B (.y) */       \
        const int tb_ = tile_ * TILE;                                        \
        _Pragma("unroll")                                                    \
        for (int rr = 0; rr < 6; ++rr) {                                     \
            const int ck_  = 4 * rr + fh;                                    \
            const int ckc_ = (ck_ < TRIPLES) ? ck_ : (TRIPLES - 1);          \
            const int rb_  = (3 * ckc_) * SMS + tw;                          \
            const v2f S0_ = sS[rb_], S1_ = sS[rb_ + SMS], S2_ = sS[rb_ + 2 * SMS]; \
            const v2f M0_ = sM[rb_], M1_ = sM[rb_ + SMS], M2_ = sM[rb_ + 2 * SMS]; \
            const v2f P_  = (S0_ * S1_) * S2_;                               \
            const v2f Ms_ = (M0_ + M1_) + M2_;                               \
            const v2f L_  = vfma(Ms_, vsplat(invCc2), P_);                   \
            const bool okA_ = (ck_ < TRIPLES) && (traj0 + ck_ < n_traj);     \
            const bool okB_ = (ck_ < TRIPLES) &&                             \
                              (traj0 + TRIPLES + ck_ < n_traj);              \
            if (okA_) out[(size_t)(traj0 + ck_) * T + tb_ + tw] = L_.x;      \
            if (okB_) out[(size_t)(traj0 + TRIPLES + ck_) * T + tb_ + tw] = L_.y; \
        }                                                                    \
    } while (0)

    #pragma unroll 1
    for (int th = 0; th < NT; th += 2) {
        EKF_PHASE(zA, zB, th);
        EKF_PHASE(zB, zA, th + 1);
    }

#undef EKF_PHASE
}

extern "C" void kernel_launch(void* const* d_in, const int* in_sizes, int n_in,
                              void* d_out, int out_size, void* d_ws, size_t ws_size,
                              hipStream_t stream) {
    const float* meas = (const float*)d_in[0];
    const float* init_state = (const float*)d_in[1];
    const float* dyna = (const float*)d_in[2];
    const float* Qm  = (const float*)d_in[3];
    const float* Rm  = (const float*)d_in[4];
    const float* P0m = (const float*)d_in[5];
    float* out = (float*)d_out;

    const int n_traj = in_sizes[1] / 6;
    const int T = in_sizes[0] / (n_traj * 3);

    const int grid = (n_traj + 2 * TRIPLES - 1) / (2 * TRIPLES);
    ekf_kernel<<<grid, 64, 0, stream>>>(meas, init_state, dyna, Qm, Rm, P0m,
                                        out, n_traj, T);
}

// Round 5
// 112.497 us; speedup vs baseline: 1.2283x; 1.2283x over previous
//
#include <hip/hip_runtime.h>
#include <math.h>

// EKF over 2048 trajectories, T=512 serial steps; lane 3k+j = subsystem j of
// trajectory k (21 traj/wave), three independent 2-state/1-meas Kalman
// filters per trajectory. Solo-wave blocks; regime (R10-R12 A/B): per step
// ~124 cyc = ~62 issue (28 ops x 2.2) + ~62 EXPOSED dep latency. R12 proved
// the exposure is hideable (2-chain interleave: 187 < 2x124) but wave-count
// makes 2-chains/lane a net loss. R13 hides it WITHIN the solo step instead.
//
// R13 (this round): revert to R11 structure (49.1 us) + compile-time
// schedule shaping via sched_group_barrier: per step force
//   {VMEM_READ x1, TRANS x1, VALU x7, TRANS x1, VALU x7, TRANS x1, VALU x8,
//    DS_WRITE x1}
// so each trans (exp2, rcp, rcp) latency is covered by independent VALU issue
// (S-chain / P-updates / state ops), and the 32 next-tile prefetch loads +
// per-step (S,m) ds_write_b64 fill remaining gaps. (S,m) now written per-step
// at immediate offsets into the SAME layout R11's b128 flush reads.
// Directives are semantically neutral (compile-time order only).

#define TRIPLES 21
#define TILE    32
#define SMS4    17               // sSM4 row stride in float4 (16 pairs + 1 pad)

__device__ __forceinline__ float frcp(float x) { return __builtin_amdgcn_rcpf(x); }

// LLVM SchedGroupMask (per CK ck_tile/core/arch/arch.hpp)
#define SGB(mask, n) __builtin_amdgcn_sched_group_barrier((mask), (n), 0)
#define SG_VALU   0x002
#define SG_VMEM_R 0x020
#define SG_DS_W   0x200
#define SG_TRANS  0x400

__global__ __launch_bounds__(64, 1) void ekf_kernel(
    const float* __restrict__ meas,        // (n_traj, T, 3)
    const float* __restrict__ init_state,  // (n_traj, 6)
    const float* __restrict__ dyna,        // (4,)
    const float* __restrict__ Qm,          // (6,6)
    const float* __restrict__ Rm,          // (3,3)
    const float* __restrict__ P0m,         // (6,6)
    float* __restrict__ out,               // (n_traj*T,)
    int n_traj, int T)
{
    // 72 rows: flush round rr=5 reads rows up to 3*23+2 = 71 (stores guarded,
    // reads stay in-bounds; rows >= 63 hold garbage, never stored).
    __shared__ float4 sSM4[72 * SMS4];     // 19,584 B
    float2* const sSM2 = (float2*)sSM4;    // same layout, float2 granularity

    const int lane  = threadIdx.x;         // 0..63
    const int k     = lane / 3;
    const int j     = lane - 3 * k;        // subsystem 0=x,1=y,2=theta
    const int traj0 = blockIdx.x * TRIPLES;
    const int kk    = (k < TRIPLES) ? k : (TRIPLES - 1);
    const int traj  = traj0 + kk;
    const int traj_eff = (traj < n_traj) ? traj : (n_traj - 1);

    const int NT = T / TILE;               // 16
    const int T3 = 3 * T;

    // ---- filter constants (theta block is linear: ca=1, cf=0) ----
    const float DTc = 1.0f / 120.0f;
    const float Cc  = 288.53900817779268f; // 200/ln2
    const float invCc2 = 1.0f / (Cc * Cc);
    const float fric = dyna[0], damp = dyna[1];
    const bool  lin = (j == 2);
    const float ca  = lin ? 1.0f : (1.0f - DTc * damp);
    const float cf  = lin ? 0.0f : (DTc * fric);
    const float cb  = 100.0f * cf;
    const float m4cb  = -4.0f * cb;
    const float cf2Cc = 2.0f * (cf * Cc);
    const float mcfCc = -(cf * Cc);
    const int pi = (j == 0) ? 0 : (j == 1) ? 1 : 4;
    const int vi = lin ? 5 : (pi + 2);     // theta velocity is state 5
    const float qp = Qm[pi * 7], qv = Qm[vi * 7], qc = Qm[pi * 6 + vi];
    const float r   = Rm[j * 4];
    const float nr2 = -r * r;
    const float w0  = r + r + qp;          // w' = nr2*rs + w0
    float p02 = P0m[pi * 6 + vi], p22 = P0m[vi * 7];
    float w   = P0m[pi * 7] + qp + r;      // w = p00 + qp + r (carried)
    float posC = Cc * init_state[traj_eff * 6 + pi];
    float xv   = Cc * init_state[traj_eff * 6 + vi];

    // ---- flush mapping: 4 traj rows/round, 16 t-pairs/row, float2 stores ----
    const int fh = lane >> 4;              // 0..3 traj row within round
    const int tw = lane & 15;              // t-pair index
    const int fb0 = (3 * fh) * SMS4 + tw;  // float4 index, rr=0, subsys 0
    float* const obase = out + (size_t)(traj0 + fh) * T + 2 * tw;

    // ---- per-step (S,m) write base: float2 index, +tl immediate per step ----
    float2* const smw = sSM2 + lane * (2 * SMS4);

    // ---- per-lane z stream: stride-3 floats, prefetched a tile ahead ----
    const float* __restrict__ zlane = meas + (size_t)traj_eff * T3 + j;

    float zA[TILE], zB[TILE];
    #pragma unroll
    for (int tl = 0; tl < TILE; ++tl) zA[tl] = zlane[3 * tl];   // tile 0

#define EKF_PHASE(ZC, ZN, TIDX)                                              \
    do {                                                                     \
        const int tile_ = (TIDX);                                            \
        const int nt_   = (tile_ + 1 < NT) ? (tile_ + 1) : tile_;            \
        const float* __restrict__ znp_ = zlane + 96 * nt_;                   \
        _Pragma("unroll")                                                    \
        for (int tl = 0; tl < TILE; ++tl) ZN[tl] = znp_[3 * tl];             \
        _Pragma("unroll")                                                    \
        for (int tl = 0; tl < TILE; ++tl) {                                  \
            const float z    = ZC[tl];                                       \
            const float e    = exp2f(xv);           /* 2^(Cc*vel) */         \
            const float ie   = frcp(e + 1.0f);                               \
            const float t    = fmaf(-ie, ie, ie);   /* ie - ie^2 */          \
            const float a    = fmaf(m4cb, t, ca);                            \
            const float u    = fmaf(DTc, p22, p02);                          \
            const float wp   = fmaf(DTc, p02, w);                            \
            const float S    = fmaf(DTc, u, wp);    /* = pp00 + r */         \
            const float rs   = frcp(S);                                      \
            const float spC  = fmaf(DTc, xv, posC);                          \
            const float yvC  = fmaf(Cc, z, -spC);                            \
            const float rsyC = rs * yvC;                                     \
            const float pp02 = fmaf(a, u, qc);                               \
            const float ap   = a * p22;                                      \
            const float pp22 = fmaf(ap, a, qv);                              \
            const float sviC = fmaf(ca, xv, mcfCc);                          \
            const float svC  = fmaf(cf2Cc, ie, sviC);                        \
            xv   = fmaf(pp02, rsyC, svC);                                    \
            const float pp00 = S - r;                                        \
            posC = fmaf(pp00, rsyC, spC);                                    \
            w    = fmaf(nr2, rs, w0);                                        \
            const float k1 = pp02 * rs;                                      \
            p02 = r * k1;                                                    \
            p22 = fmaf(-k1, pp02, pp22);                                     \
            smw[tl] = make_float2(S, yvC * rsyC);   /* ds_write_b64 +imm */  \
            /* schedule shaping: spread trans latency over independent ops */\
            SGB(SG_VMEM_R, 1);   /* one next-tile prefetch load */           \
            SGB(SG_TRANS,  1);   /* exp2 */                                  \
            SGB(SG_VALU,   7);                                               \
            SGB(SG_TRANS,  1);   /* rcp(e+1) */                              \
            SGB(SG_VALU,   7);                                               \
            SGB(SG_TRANS,  1);   /* rcp(S) */                                \
            SGB(SG_VALU,   8);                                               \
            SGB(SG_DS_W,   1);   /* (S,m) pair */                            \
        }                                                                    \
        /* flush: 6 rounds x (3 ds_read_b128 + float2 store) */              \
        const int tb_ = tile_ * TILE;                                        \
        _Pragma("unroll")                                                    \
        for (int rr = 0; rr < 6; ++rr) {                                     \
            const int ck_ = 4 * rr + fh;                                     \
            const bool ok_ = (ck_ < TRIPLES) && (traj0 + ck_ < n_traj);      \
            const float4 a0_ = sSM4[fb0 + 204 * rr];                         \
            const float4 a1_ = sSM4[fb0 + 204 * rr + SMS4];                  \
            const float4 a2_ = sSM4[fb0 + 204 * rr + 2 * SMS4];              \
            const float l0_ = fmaf(a0_.y + a1_.y + a2_.y, invCc2,            \
                                   (a0_.x * a1_.x) * a2_.x);                 \
            const float l1_ = fmaf(a0_.w + a1_.w + a2_.w, invCc2,            \
                                   (a0_.z * a1_.z) * a2_.z);                 \
            if (ok_) *(float2*)(obase + tb_ + rr * (4 * T)) =                \
                make_float2(l0_, l1_);                                       \
        }                                                                    \
    } while (0)

    #pragma unroll 1
    for (int th = 0; th < NT; th += 2) {
        EKF_PHASE(zA, zB, th);
        EKF_PHASE(zB, zA, th + 1);
    }

#undef EKF_PHASE
}

extern "C" void kernel_launch(void* const* d_in, const int* in_sizes, int n_in,
                              void* d_out, int out_size, void* d_ws, size_t ws_size,
                              hipStream_t stream) {
    const float* meas = (const float*)d_in[0];
    const float* init_state = (const float*)d_in[1];
    const float* dyna = (const float*)d_in[2];
    const float* Qm  = (const float*)d_in[3];
    const float* Rm  = (const float*)d_in[4];
    const float* P0m = (const float*)d_in[5];
    float* out = (float*)d_out;

    const int n_traj = in_sizes[1] / 6;
    const int T = in_sizes[0] / (n_traj * 3);

    const int grid = (n_traj + TRIPLES - 1) / TRIPLES;
    ekf_kernel<<<grid, 64, 0, stream>>>(meas, init_state, dyna, Qm, Rm, P0m,
                                        out, n_traj, T);
}

// Round 6
// 104.184 us; speedup vs baseline: 1.3263x; 1.0798x over previous
//
#include <hip/hip_runtime.h>
#include <math.h>

// EKF over 2048 trajectories, T=512 serial steps; lane 3k+j = subsystem j of
// trajectory k (21 traj/wave), three independent 2-state/1-meas Kalman
// filters per trajectory. Latency-bound serial chain; wall = 512 x per-step.
//
// R9:  z register double-buffer; carried w = p00+qp+r.
// R10: 27->25-op step body (exact algebra).   R11: scaled state (xv=Cc*vel),
// tanh-free a via ie-ie^2, packed (S,m); 49.1 us.  R13: SGB schedule shaping
// = NULL -> stall is chain latency + issue, not compiler ordering.
//
// R14 (this round): producer/consumer wave specialization. Wave 0 = compute
// (step chain only: 25 VALU, 0.25 ds_read + 0.5 ds_write per step, zero
// global ops, zero vmcnt waits). Wave 1 = service: stages each z-tile into
// LDS transposed (compute reads 1 ds_read_b128 per 4 steps), and performs
// the whole (S,m)->loss flush from double-buffered sSM. One uniform
// __syncthreads per tile. Step math is bit-identical to R11.

#define TRIPLES 21
#define TILE    32
#define SMS4    17               // sSM row stride in float4 (16 pairs + 1 pad)

__device__ __forceinline__ float frcp(float x) { return __builtin_amdgcn_rcpf(x); }

__global__ __launch_bounds__(128, 1) void ekf_kernel(
    const float* __restrict__ meas,        // (n_traj, T, 3)
    const float* __restrict__ init_state,  // (n_traj, 6)
    const float* __restrict__ dyna,        // (4,)
    const float* __restrict__ Qm,          // (6,6)
    const float* __restrict__ Rm,          // (3,3)
    const float* __restrict__ P0m,         // (6,6)
    float* __restrict__ out,               // (n_traj*T,)
    int n_traj, int T)
{
    // z tiles: [buf][t-chunk][compute-lane] float4 = 32 KB.
    __shared__ float4 zs4[2][TILE / 4][64];
    // (S,m) pairs: [buf][72 rows x SMS4] float4 = 39.2 KB (flush round rr=5
    // reads rows up to 71; stores guarded, reads in-bounds, rows>=63 garbage).
    __shared__ float4 sSM4[2][72 * SMS4];

    const int tid   = threadIdx.x;
    const int wid   = tid >> 6;            // 0 = compute, 1 = service
    const int lane  = tid & 63;
    const int k     = lane / 3;
    const int j     = lane - 3 * k;        // subsystem 0=x,1=y,2=theta
    const int traj0 = blockIdx.x * TRIPLES;
    const int kk    = (k < TRIPLES) ? k : (TRIPLES - 1);
    const int traj  = traj0 + kk;
    const int traj_eff = (traj < n_traj) ? traj : (n_traj - 1);

    const int NT = T / TILE;               // 16
    const int T3 = 3 * T;

    // ---- filter constants (theta block is linear: ca=1, cf=0) ----
    const float DTc = 1.0f / 120.0f;
    const float Cc  = 288.53900817779268f; // 200/ln2
    const float invCc2 = 1.0f / (Cc * Cc);
    const float fric = dyna[0], damp = dyna[1];
    const bool  lin = (j == 2);
    const float ca  = lin ? 1.0f : (1.0f - DTc * damp);
    const float cf  = lin ? 0.0f : (DTc * fric);
    const float cb  = 100.0f * cf;
    const float m4cb  = -4.0f * cb;
    const float cf2Cc = 2.0f * (cf * Cc);
    const float mcfCc = -(cf * Cc);
    const int pi = (j == 0) ? 0 : (j == 1) ? 1 : 4;
    const int vi = lin ? 5 : (pi + 2);     // theta velocity is state 5
    const float qp = Qm[pi * 7], qv = Qm[vi * 7], qc = Qm[pi * 6 + vi];
    const float r   = Rm[j * 4];
    const float nr2 = -r * r;
    const float w0  = r + r + qp;          // w' = nr2*rs + w0
    float p02 = P0m[pi * 6 + vi], p22 = P0m[vi * 7];
    float w   = P0m[pi * 7] + qp + r;      // w = p00 + qp + r (carried)
    float posC = Cc * init_state[traj_eff * 6 + pi];
    float xv   = Cc * init_state[traj_eff * 6 + vi];

    // ---- service-side invariants ----
    const int fh = lane >> 4;              // 0..3 traj row within flush round
    const int tw = lane & 15;              // t-pair index
    const int fb0 = (3 * fh) * SMS4 + tw;  // float4 index, rr=0, subsys 0
    float* const obase = out + (size_t)(traj0 + fh) * T + 2 * tw;
    const float* __restrict__ zlane = meas + (size_t)traj_eff * T3 + j;

    // ---- service: stage z tile into zs4[buf] (transposed) ----
#define STAGE(TIDX, BUF)                                                     \
    do {                                                                     \
        const float* __restrict__ zp_ = zlane + 96 * (TIDX);                 \
        _Pragma("unroll")                                                    \
        for (int tt = 0; tt < TILE; ++tt)                                    \
            ((float*)&zs4[BUF][tt >> 2][lane])[tt & 3] = zp_[3 * tt];        \
    } while (0)

    // ---- service: flush tile's (S,m) -> losses ----
#define FLUSH(TIDX, BUF)                                                     \
    do {                                                                     \
        const int tb_ = (TIDX) * TILE;                                       \
        _Pragma("unroll")                                                    \
        for (int rr = 0; rr < 6; ++rr) {                                     \
            const int ck_ = 4 * rr + fh;                                     \
            const bool ok_ = (ck_ < TRIPLES) && (traj0 + ck_ < n_traj);      \
            const float4 a0_ = sSM4[BUF][fb0 + 204 * rr];                    \
            const float4 a1_ = sSM4[BUF][fb0 + 204 * rr + SMS4];             \
            const float4 a2_ = sSM4[BUF][fb0 + 204 * rr + 2 * SMS4];         \
            const float l0_ = fmaf(a0_.y + a1_.y + a2_.y, invCc2,            \
                                   (a0_.x * a1_.x) * a2_.x);                 \
            const float l1_ = fmaf(a0_.w + a1_.w + a2_.w, invCc2,            \
                                   (a0_.z * a1_.z) * a2_.z);                 \
            if (ok_) *(float2*)(obase + tb_ + rr * (4 * T)) =                \
                make_float2(l0_, l1_);                                       \
        }                                                                    \
    } while (0)

    // ---- compute: one EKF step (R11 body, bit-identical) ----
#define STEP(ZZ, TL)                                                         \
    do {                                                                     \
        const float z    = (ZZ);                                             \
        const float e    = exp2f(xv);           /* 2^(Cc*vel) */             \
        const float ie   = frcp(e + 1.0f);                                   \
        const float t    = fmaf(-ie, ie, ie);   /* ie - ie^2 */              \
        const float a    = fmaf(m4cb, t, ca);                                \
        const float u    = fmaf(DTc, p22, p02);                              \
        const float wp   = fmaf(DTc, p02, w);                                \
        const float S    = fmaf(DTc, u, wp);    /* = pp00 + r */             \
        const float rs   = frcp(S);                                          \
        const float spC  = fmaf(DTc, xv, posC);                              \
        const float yvC  = fmaf(Cc, z, -spC);                                \
        const float rsyC = rs * yvC;                                         \
        const float pp02 = fmaf(a, u, qc);                                   \
        const float ap   = a * p22;                                          \
        const float pp22 = fmaf(ap, a, qv);                                  \
        const float sviC = fmaf(ca, xv, mcfCc);                              \
        const float svC  = fmaf(cf2Cc, ie, sviC);                            \
        xv   = fmaf(pp02, rsyC, svC);                                        \
        const float pp00 = S - r;                                            \
        posC = fmaf(pp00, rsyC, spC);                                        \
        w    = fmaf(nr2, rs, w0);                                            \
        const float k1 = pp02 * rs;                                          \
        p02 = r * k1;                                                        \
        p22 = fmaf(-k1, pp02, pp22);                                         \
        Sv[TL] = S;                                                          \
        Mv[TL] = yvC * rsyC;                                                 \
    } while (0)

    int cur = 0;
    if (wid == 1) STAGE(0, 0);
    __syncthreads();

    #pragma unroll 1
    for (int tile = 0; tile < NT; ++tile) {
        if (wid == 0) {
            float Sv[TILE], Mv[TILE];
            #pragma unroll
            for (int q = 0; q < TILE / 4; ++q) {
                const float4 zq = zs4[cur][q][lane];
                STEP(zq.x, 4 * q + 0);
                STEP(zq.y, 4 * q + 1);
                STEP(zq.z, 4 * q + 2);
                STEP(zq.w, 4 * q + 3);
            }
            #pragma unroll
            for (int h = 0; h < TILE / 2; ++h)
                sSM4[cur][lane * SMS4 + h] =
                    make_float4(Sv[2*h], Mv[2*h], Sv[2*h+1], Mv[2*h+1]);
        } else {
            if (tile + 1 < NT) STAGE(tile + 1, cur ^ 1);
            if (tile > 0)      FLUSH(tile - 1, cur ^ 1);
        }
        __syncthreads();                   // uniform: outside the role branch
        cur ^= 1;
    }
    if (wid == 1) FLUSH(NT - 1, cur ^ 1);  // last tile's buffer

#undef STEP
#undef FLUSH
#undef STAGE
}

extern "C" void kernel_launch(void* const* d_in, const int* in_sizes, int n_in,
                              void* d_out, int out_size, void* d_ws, size_t ws_size,
                              hipStream_t stream) {
    const float* meas = (const float*)d_in[0];
    const float* init_state = (const float*)d_in[1];
    const float* dyna = (const float*)d_in[2];
    const float* Qm  = (const float*)d_in[3];
    const float* Rm  = (const float*)d_in[4];
    const float* P0m = (const float*)d_in[5];
    float* out = (float*)d_out;

    const int n_traj = in_sizes[1] / 6;
    const int T = in_sizes[0] / (n_traj * 3);

    const int grid = (n_traj + TRIPLES - 1) / TRIPLES;
    ekf_kernel<<<grid, 128, 0, stream>>>(meas, init_state, dyna, Qm, Rm, P0m,
                                         out, n_traj, T);
}

// Round 7
// 103.781 us; speedup vs baseline: 1.3315x; 1.0039x over previous
//
#include <hip/hip_runtime.h>
#include <math.h>

// EKF over 2048 trajectories, T=512 serial steps; lane 3k+j = subsystem j of
// trajectory k (21 traj/wave), three independent 2-state/1-meas Kalman
// filters per trajectory. Latency-bound serial chain; wall = 512 x per-step.
//
// R14: producer/consumer wave specialization (compute wave = pure step chain;
// service wave = z staging + (S,m) flush; 1 uniform barrier/tile). ~41 us.
//
// R15 (this round): shed 2 more ops off the compute wave + shorten the
// carried xv cycle by 1 link (all exact algebra):
//  - service pre-scales z -> zC = Cc*z during staging; compute uses
//    yvC = zC - spC and posC' = fma(-r, rsyC, zC)  [replaces pp00 + posC fma;
//    identity: spC + (S-r)*rs*yvC = zC - r*rs*yvC up to frcp ulp]
//  - Mahalanobis moves to service: compute stores (S, yvC); service flush
//    computes y^2 * rcp(S) (slack-rich, deterministic)
//  - pp02 = fma(m4cb*u, t, fma(ca,u,qc)): helper ops depend only on u
//    (issue in the trans shadow), removing 'a' from the t->pp02->xv' path.
//    'a' remains for the off-cycle pp22.
// Compute body: 25 ops (3 trans + 22 VALU), carried cycle 7 -> 6 links.

#define TRIPLES 21
#define TILE    32
#define SMS4    17               // sSM row stride in float4 (16 pairs + 1 pad)

__device__ __forceinline__ float frcp(float x) { return __builtin_amdgcn_rcpf(x); }

__global__ __launch_bounds__(128, 1) void ekf_kernel(
    const float* __restrict__ meas,        // (n_traj, T, 3)
    const float* __restrict__ init_state,  // (n_traj, 6)
    const float* __restrict__ dyna,        // (4,)
    const float* __restrict__ Qm,          // (6,6)
    const float* __restrict__ Rm,          // (3,3)
    const float* __restrict__ P0m,         // (6,6)
    float* __restrict__ out,               // (n_traj*T,)
    int n_traj, int T)
{
    // z tiles (pre-scaled by Cc): [buf][t-chunk][compute-lane] float4 = 16 KB.
    __shared__ float4 zs4[2][TILE / 4][64];
    // (S,y) pairs: [buf][72 rows x SMS4] float4 = 39.2 KB (flush round rr=5
    // reads rows up to 71; stores guarded, reads in-bounds, rows>=63 garbage).
    __shared__ float4 sSM4[2][72 * SMS4];

    const int tid   = threadIdx.x;
    const int wid   = tid >> 6;            // 0 = compute, 1 = service
    const int lane  = tid & 63;
    const int k     = lane / 3;
    const int j     = lane - 3 * k;        // subsystem 0=x,1=y,2=theta
    const int traj0 = blockIdx.x * TRIPLES;
    const int kk    = (k < TRIPLES) ? k : (TRIPLES - 1);
    const int traj  = traj0 + kk;
    const int traj_eff = (traj < n_traj) ? traj : (n_traj - 1);

    const int NT = T / TILE;               // 16
    const int T3 = 3 * T;

    // ---- filter constants (theta block is linear: ca=1, cf=0) ----
    const float DTc = 1.0f / 120.0f;
    const float Cc  = 288.53900817779268f; // 200/ln2
    const float invCc2 = 1.0f / (Cc * Cc);
    const float fric = dyna[0], damp = dyna[1];
    const bool  lin = (j == 2);
    const float ca  = lin ? 1.0f : (1.0f - DTc * damp);
    const float cf  = lin ? 0.0f : (DTc * fric);
    const float cb  = 100.0f * cf;
    const float m4cb  = -4.0f * cb;
    const float cf2Cc = 2.0f * (cf * Cc);
    const float mcfCc = -(cf * Cc);
    const int pi = (j == 0) ? 0 : (j == 1) ? 1 : 4;
    const int vi = lin ? 5 : (pi + 2);     // theta velocity is state 5
    const float qp = Qm[pi * 7], qv = Qm[vi * 7], qc = Qm[pi * 6 + vi];
    const float r   = Rm[j * 4];
    const float nr2 = -r * r;
    const float w0  = r + r + qp;          // w' = nr2*rs + w0
    float p02 = P0m[pi * 6 + vi], p22 = P0m[vi * 7];
    float w   = P0m[pi * 7] + qp + r;      // w = p00 + qp + r (carried)
    float posC = Cc * init_state[traj_eff * 6 + pi];
    float xv   = Cc * init_state[traj_eff * 6 + vi];

    // ---- service-side invariants ----
    const int fh = lane >> 4;              // 0..3 traj row within flush round
    const int tw = lane & 15;              // t-pair index
    const int fb0 = (3 * fh) * SMS4 + tw;  // float4 index, rr=0, subsys 0
    float* const obase = out + (size_t)(traj0 + fh) * T + 2 * tw;
    const float* __restrict__ zlane = meas + (size_t)traj_eff * T3 + j;

    // ---- service: stage z tile into zs4[buf] (transposed, pre-scaled) ----
#define STAGE(TIDX, BUF)                                                     \
    do {                                                                     \
        const float* __restrict__ zp_ = zlane + 96 * (TIDX);                 \
        _Pragma("unroll")                                                    \
        for (int tt = 0; tt < TILE; ++tt)                                    \
            ((float*)&zs4[BUF][tt >> 2][lane])[tt & 3] = Cc * zp_[3 * tt];   \
    } while (0)

    // ---- service: flush tile's (S,y) -> losses (Mahalanobis here) ----
#define FLUSH(TIDX, BUF)                                                     \
    do {                                                                     \
        const int tb_ = (TIDX) * TILE;                                       \
        _Pragma("unroll")                                                    \
        for (int rr = 0; rr < 6; ++rr) {                                     \
            const int ck_ = 4 * rr + fh;                                     \
            const bool ok_ = (ck_ < TRIPLES) && (traj0 + ck_ < n_traj);      \
            const float4 a0_ = sSM4[BUF][fb0 + 204 * rr];                    \
            const float4 a1_ = sSM4[BUF][fb0 + 204 * rr + SMS4];             \
            const float4 a2_ = sSM4[BUF][fb0 + 204 * rr + 2 * SMS4];         \
            const float m0e_ = (a0_.y * a0_.y) * frcp(a0_.x);                \
            const float m1e_ = (a1_.y * a1_.y) * frcp(a1_.x);                \
            const float m2e_ = (a2_.y * a2_.y) * frcp(a2_.x);                \
            const float m0o_ = (a0_.w * a0_.w) * frcp(a0_.z);                \
            const float m1o_ = (a1_.w * a1_.w) * frcp(a1_.z);                \
            const float m2o_ = (a2_.w * a2_.w) * frcp(a2_.z);                \
            const float l0_ = fmaf(m0e_ + m1e_ + m2e_, invCc2,               \
                                   (a0_.x * a1_.x) * a2_.x);                 \
            const float l1_ = fmaf(m0o_ + m1o_ + m2o_, invCc2,               \
                                   (a0_.z * a1_.z) * a2_.z);                 \
            if (ok_) *(float2*)(obase + tb_ + rr * (4 * T)) =                \
                make_float2(l0_, l1_);                                       \
        }                                                                    \
    } while (0)

    // ---- compute: one EKF step (exact algebra, 25 ops, 6-link cycle) ----
#define STEP(ZZ, TL)                                                         \
    do {                                                                     \
        const float zC   = (ZZ);                    /* Cc*z (pre-scaled) */  \
        const float e    = exp2f(xv);               /* 2^(Cc*vel) */         \
        const float ie   = frcp(e + 1.0f);                                   \
        const float t    = fmaf(-ie, ie, ie);       /* ie - ie^2 */          \
        const float u    = fmaf(DTc, p22, p02);                              \
        const float m4u  = m4cb * u;                /* trans-shadow */       \
        const float cuq  = fmaf(ca, u, qc);         /* trans-shadow */       \
        const float a    = fmaf(m4cb, t, ca);       /* off-cycle: pp22 */    \
        const float wp   = fmaf(DTc, p02, w);                                \
        const float S    = fmaf(DTc, u, wp);        /* = pp00 + r */         \
        const float rs   = frcp(S);                                          \
        const float spC  = fmaf(DTc, xv, posC);                              \
        const float yvC  = zC - spC;                                         \
        const float rsyC = rs * yvC;                                         \
        const float pp02 = fmaf(m4u, t, cuq);       /* t -> pp02 direct */   \
        const float ap   = a * p22;                                          \
        const float pp22 = fmaf(ap, a, qv);                                  \
        const float sviC = fmaf(ca, xv, mcfCc);                              \
        const float svC  = fmaf(cf2Cc, ie, sviC);                            \
        xv   = fmaf(pp02, rsyC, svC);                                        \
        posC = fmaf(-r, rsyC, zC);                  /* = spC+(S-r)rs*y */    \
        w    = fmaf(nr2, rs, w0);                                            \
        const float k1 = pp02 * rs;                                          \
        p02 = r * k1;                                                        \
        p22 = fmaf(-k1, pp02, pp22);                                         \
        Sv[TL] = S;                                                          \
        Yv[TL] = yvC;                                                        \
    } while (0)

    int cur = 0;
    if (wid == 1) STAGE(0, 0);
    __syncthreads();

    #pragma unroll 1
    for (int tile = 0; tile < NT; ++tile) {
        if (wid == 0) {
            float Sv[TILE], Yv[TILE];
            #pragma unroll
            for (int q = 0; q < TILE / 4; ++q) {
                const float4 zq = zs4[cur][q][lane];
                STEP(zq.x, 4 * q + 0);
                STEP(zq.y, 4 * q + 1);
                STEP(zq.z, 4 * q + 2);
                STEP(zq.w, 4 * q + 3);
            }
            #pragma unroll
            for (int h = 0; h < TILE / 2; ++h)
                sSM4[cur][lane * SMS4 + h] =
                    make_float4(Sv[2*h], Yv[2*h], Sv[2*h+1], Yv[2*h+1]);
        } else {
            if (tile + 1 < NT) STAGE(tile + 1, cur ^ 1);
            if (tile > 0)      FLUSH(tile - 1, cur ^ 1);
        }
        __syncthreads();                   // uniform: outside the role branch
        cur ^= 1;
    }
    if (wid == 1) FLUSH(NT - 1, cur ^ 1);  // last tile's buffer

#undef STEP
#undef FLUSH
#undef STAGE
}

extern "C" void kernel_launch(void* const* d_in, const int* in_sizes, int n_in,
                              void* d_out, int out_size, void* d_ws, size_t ws_size,
                              hipStream_t stream) {
    const float* meas = (const float*)d_in[0];
    const float* init_state = (const float*)d_in[1];
    const float* dyna = (const float*)d_in[2];
    const float* Qm  = (const float*)d_in[3];
    const float* Rm  = (const float*)d_in[4];
    const float* P0m = (const float*)d_in[5];
    float* out = (float*)d_out;

    const int n_traj = in_sizes[1] / 6;
    const int T = in_sizes[0] / (n_traj * 3);

    const int grid = (n_traj + TRIPLES - 1) / TRIPLES;
    ekf_kernel<<<grid, 128, 0, stream>>>(meas, init_state, dyna, Qm, Rm, P0m,
                                         out, n_traj, T);
}

// Round 9
// 103.261 us; speedup vs baseline: 1.3382x; 1.0050x over previous
//
#include <hip/hip_runtime.h>
#include <math.h>

// EKF over 2048 trajectories, T=512 serial steps; lane 3k+j = subsystem j of
// trajectory k (21 traj/wave), three independent 2-state/1-meas Kalman
// filters per trajectory. Latency-bound serial chain; wall = 512 x per-step.
//
// R14: producer/consumer wave specialization (compute wave = pure step chain;
// service wave = z staging + flush; 1 uniform barrier/tile). ~41 us warm.
// R15: z pre-scaled by Cc in staging; posC' = fma(-r,rsyC,zC); Mahalanobis
// moved to service flush. ~flat -> compute wave is ISSUE-bound; chain slack.
//
// R16 (re-submit; previous round died on macro name-capture: the fused-rcp
// local 'q' shadowed the loop counter inside STEP -> renamed q_ / qq):
// transcendental count 3 -> 2 per step via single-rcp fusion (and revert
// R15's pp02 split, -2 VALU, chain-shortening proven worthless):
//   e = fmin(exp2(xv), 1e30)          // clamp: keeps rs finite at saturation
//   P = fma(e, S, S)                  // (e+1)*S
//   q_ = rcp(P)                       // ONE rcp replaces rcp(e+1), rcp(S)
//   ie = S*q_                         // ~ 1/(e+1)  (sigmoid)
//   rs = fma(e, q_, q_)               // ~ 1/S
// e=0 (underflow): P=S, rs=q_=rcp(S) exact. e=1e30: ie~1e-30 -> t=0, tanh=1,
// saturation exact. Step = 23 VALU + 2 trans. This is also the trans-rate
// discriminator: -14 cyc/step if trans issue at 1/8 rate, -6 if 1/4, flat
// if full-rate.

#define TRIPLES 21
#define TILE    32
#define SMS4    17               // sSM row stride in float4 (16 pairs + 1 pad)

__device__ __forceinline__ float frcp(float x) { return __builtin_amdgcn_rcpf(x); }

__global__ __launch_bounds__(128, 1) void ekf_kernel(
    const float* __restrict__ meas,        // (n_traj, T, 3)
    const float* __restrict__ init_state,  // (n_traj, 6)
    const float* __restrict__ dyna,        // (4,)
    const float* __restrict__ Qm,          // (6,6)
    const float* __restrict__ Rm,          // (3,3)
    const float* __restrict__ P0m,         // (6,6)
    float* __restrict__ out,               // (n_traj*T,)
    int n_traj, int T)
{
    // z tiles (pre-scaled by Cc): [buf][t-chunk][compute-lane] float4 = 16 KB.
    __shared__ float4 zs4[2][TILE / 4][64];
    // (S,y) pairs: [buf][72 rows x SMS4] float4 = 39.2 KB (flush round rr=5
    // reads rows up to 71; stores guarded, reads in-bounds, rows>=63 garbage).
    __shared__ float4 sSM4[2][72 * SMS4];

    const int tid   = threadIdx.x;
    const int wid   = tid >> 6;            // 0 = compute, 1 = service
    const int lane  = tid & 63;
    const int k     = lane / 3;
    const int j     = lane - 3 * k;        // subsystem 0=x,1=y,2=theta
    const int traj0 = blockIdx.x * TRIPLES;
    const int kk    = (k < TRIPLES) ? k : (TRIPLES - 1);
    const int traj  = traj0 + kk;
    const int traj_eff = (traj < n_traj) ? traj : (n_traj - 1);

    const int NT = T / TILE;               // 16
    const int T3 = 3 * T;

    // ---- filter constants (theta block is linear: ca=1, cf=0) ----
    const float DTc = 1.0f / 120.0f;
    const float Cc  = 288.53900817779268f; // 200/ln2
    const float invCc2 = 1.0f / (Cc * Cc);
    const float fric = dyna[0], damp = dyna[1];
    const bool  lin = (j == 2);
    const float ca  = lin ? 1.0f : (1.0f - DTc * damp);
    const float cf  = lin ? 0.0f : (DTc * fric);
    const float cb  = 100.0f * cf;
    const float m4cb  = -4.0f * cb;
    const float cf2Cc = 2.0f * (cf * Cc);
    const float mcfCc = -(cf * Cc);
    const int pi = (j == 0) ? 0 : (j == 1) ? 1 : 4;
    const int vi = lin ? 5 : (pi + 2);     // theta velocity is state 5
    const float qp = Qm[pi * 7], qv = Qm[vi * 7], qc = Qm[pi * 6 + vi];
    const float r   = Rm[j * 4];
    const float nr2 = -r * r;
    const float w0  = r + r + qp;          // w' = nr2*rs + w0
    float p02 = P0m[pi * 6 + vi], p22 = P0m[vi * 7];
    float w   = P0m[pi * 7] + qp + r;      // w = p00 + qp + r (carried)
    float posC = Cc * init_state[traj_eff * 6 + pi];
    float xv   = Cc * init_state[traj_eff * 6 + vi];

    // ---- service-side invariants ----
    const int fh = lane >> 4;              // 0..3 traj row within flush round
    const int tw = lane & 15;              // t-pair index
    const int fb0 = (3 * fh) * SMS4 + tw;  // float4 index, rr=0, subsys 0
    float* const obase = out + (size_t)(traj0 + fh) * T + 2 * tw;
    const float* __restrict__ zlane = meas + (size_t)traj_eff * T3 + j;

    // ---- service: stage z tile into zs4[buf] (transposed, pre-scaled) ----
#define STAGE(TIDX, BUF)                                                     \
    do {                                                                     \
        const float* __restrict__ zp_ = zlane + 96 * (TIDX);                 \
        _Pragma("unroll")                                                    \
        for (int tt = 0; tt < TILE; ++tt)                                    \
            ((float*)&zs4[BUF][tt >> 2][lane])[tt & 3] = Cc * zp_[3 * tt];   \
    } while (0)

    // ---- service: flush tile's (S,y) -> losses (Mahalanobis here) ----
#define FLUSH(TIDX, BUF)                                                     \
    do {                                                                     \
        const int tb_ = (TIDX) * TILE;                                       \
        _Pragma("unroll")                                                    \
        for (int rr = 0; rr < 6; ++rr) {                                     \
            const int ck_ = 4 * rr + fh;                                     \
            const bool ok_ = (ck_ < TRIPLES) && (traj0 + ck_ < n_traj);      \
            const float4 a0_ = sSM4[BUF][fb0 + 204 * rr];                    \
            const float4 a1_ = sSM4[BUF][fb0 + 204 * rr + SMS4];             \
            const float4 a2_ = sSM4[BUF][fb0 + 204 * rr + 2 * SMS4];         \
            const float m0e_ = (a0_.y * a0_.y) * frcp(a0_.x);                \
            const float m1e_ = (a1_.y * a1_.y) * frcp(a1_.x);                \
            const float m2e_ = (a2_.y * a2_.y) * frcp(a2_.x);                \
            const float m0o_ = (a0_.w * a0_.w) * frcp(a0_.z);                \
            const float m1o_ = (a1_.w * a1_.w) * frcp(a1_.z);                \
            const float m2o_ = (a2_.w * a2_.w) * frcp(a2_.z);                \
            const float l0_ = fmaf(m0e_ + m1e_ + m2e_, invCc2,               \
                                   (a0_.x * a1_.x) * a2_.x);                 \
            const float l1_ = fmaf(m0o_ + m1o_ + m2o_, invCc2,               \
                                   (a0_.z * a1_.z) * a2_.z);                 \
            if (ok_) *(float2*)(obase + tb_ + rr * (4 * T)) =                \
                make_float2(l0_, l1_);                                       \
        }                                                                    \
    } while (0)

    // ---- compute: one EKF step (23 VALU + 2 trans, single-rcp fusion) ----
#define STEP(ZZ, TL)                                                         \
    do {                                                                     \
        const float zC   = (ZZ);                    /* Cc*z (pre-scaled) */  \
        const float e0   = exp2f(xv);               /* 2^(Cc*vel) */         \
        const float e    = fminf(e0, 1e30f);        /* saturation guard */   \
        const float u    = fmaf(DTc, p22, p02);                              \
        const float wp   = fmaf(DTc, p02, w);                                \
        const float S    = fmaf(DTc, u, wp);        /* = pp00 + r */         \
        const float P    = fmaf(e, S, S);           /* (e+1)*S */            \
        const float q_   = frcp(P);                 /* the ONE rcp */        \
        const float ie   = S * q_;                  /* ~ 1/(e+1) */          \
        const float rs   = fmaf(e, q_, q_);         /* ~ 1/S */              \
        const float t    = fmaf(-ie, ie, ie);       /* ie - ie^2 */          \
        const float a    = fmaf(m4cb, t, ca);                                \
        const float pp02 = fmaf(a, u, qc);                                   \
        const float ap   = a * p22;                                          \
        const float pp22 = fmaf(ap, a, qv);                                  \
        const float spC  = fmaf(DTc, xv, posC);                              \
        const float yvC  = zC - spC;                                         \
        const float rsyC = rs * yvC;                                         \
        const float sviC = fmaf(ca, xv, mcfCc);                              \
        const float svC  = fmaf(cf2Cc, ie, sviC);                            \
        xv   = fmaf(pp02, rsyC, svC);                                        \
        posC = fmaf(-r, rsyC, zC);                  /* = spC+(S-r)rs*y */    \
        w    = fmaf(nr2, rs, w0);                                            \
        const float k1 = pp02 * rs;                                          \
        p02 = r * k1;                                                        \
        p22 = fmaf(-k1, pp02, pp22);                                         \
        Sv[TL] = S;                                                          \
        Yv[TL] = yvC;                                                        \
    } while (0)

    int cur = 0;
    if (wid == 1) STAGE(0, 0);
    __syncthreads();

    #pragma unroll 1
    for (int tile = 0; tile < NT; ++tile) {
        if (wid == 0) {
            float Sv[TILE], Yv[TILE];
            #pragma unroll
            for (int qq = 0; qq < TILE / 4; ++qq) {
                const float4 zq = zs4[cur][qq][lane];
                STEP(zq.x, 4 * qq + 0);
                STEP(zq.y, 4 * qq + 1);
                STEP(zq.z, 4 * qq + 2);
                STEP(zq.w, 4 * qq + 3);
            }
            #pragma unroll
            for (int h = 0; h < TILE / 2; ++h)
                sSM4[cur][lane * SMS4 + h] =
                    make_float4(Sv[2*h], Yv[2*h], Sv[2*h+1], Yv[2*h+1]);
        } else {
            if (tile + 1 < NT) STAGE(tile + 1, cur ^ 1);
            if (tile > 0)      FLUSH(tile - 1, cur ^ 1);
        }
        __syncthreads();                   // uniform: outside the role branch
        cur ^= 1;
    }
    if (wid == 1) FLUSH(NT - 1, cur ^ 1);  // last tile's buffer

#undef STEP
#undef FLUSH
#undef STAGE
}

extern "C" void kernel_launch(void* const* d_in, const int* in_sizes, int n_in,
                              void* d_out, int out_size, void* d_ws, size_t ws_size,
                              hipStream_t stream) {
    const float* meas = (const float*)d_in[0];
    const float* init_state = (const float*)d_in[1];
    const float* dyna = (const float*)d_in[2];
    const float* Qm  = (const float*)d_in[3];
    const float* Rm  = (const float*)d_in[4];
    const float* P0m = (const float*)d_in[5];
    float* out = (float*)d_out;

    const int n_traj = in_sizes[1] / 6;
    const int T = in_sizes[0] / (n_traj * 3);

    const int grid = (n_traj + TRIPLES - 1) / TRIPLES;
    ekf_kernel<<<grid, 128, 0, stream>>>(meas, init_state, dyna, Qm, Rm, P0m,
                                         out, n_traj, T);
}